// Round 4
// baseline (2448.552 us; speedup 1.0000x reference)
//
#include <hip/hip_runtime.h>
#include <hip/hip_bf16.h>

#define P_ 50000
#define NL_ 2000
#define NQ_ 6000
#define L_ 8
#define P2L_ 128
#define P2Q_ 64
#define D_ 32
#define ITERS_ 8

typedef __hip_bfloat16 bf16;
typedef unsigned short u16;
typedef unsigned int u32;

__device__ __forceinline__ float bfb2f(u16 u) {
    union { u32 i; float f; } c; c.i = ((u32)u) << 16; return c.f;
}
__device__ __forceinline__ u16 f2bfb(float f) {
    union { bf16 h; u16 u; } c; c.h = __float2bfloat16(f); return c.u;
}
__device__ __forceinline__ u32 pk2(float a, float b) {
    return (u32)f2bfb(a) | ((u32)f2bfb(b) << 16);
}

__device__ __forceinline__ float tanh_fast(float x) {
    // exact identity tanh(x) = 1 - 2/(e^{2x}+1); safe at both saturations
    return 1.f - 2.f / (__expf(2.f * x) + 1.f);
}

// Runtime dtype probe: read up to 64 leading elements as bf16. Legit bf16 data
// is finite and in [1e-8,1e6] or exactly 0. f32 misread as bf16 puts random
// mantissa bits in exponent fields -> insane values; error prob ~1e-24.
__device__ bool detect_f32(const void* p, int n) {
    const u16* u = (const u16*)p;
    int m = n < 64 ? n : 64;
    bool bad = false;
    for (int k = 0; k < m; k++) {
        float v = bfb2f(u[k]);
        float av = fabsf(v);
        bool sane = (v == v) && (av <= 1e6f) && (av == 0.0f || av >= 1e-8f);
        bad |= !sane;
    }
    return bad;
}

// ---------------- input canonicalization: any-dtype -> f32 in ws -------------

struct CvtArgs { const void* p[40]; };

__global__ __launch_bounds__(256) void k_convert(CvtArgs a, float* __restrict__ dst) {
    static constexpr int N[40] = {
        50000,50000,50000,50000,50000,50000,50000,50000,50000,50000,
        2000,6000,6000,
        544,32,1024,32, 160,32,1024,32, 160,32,1024,32,
        2048,1024,32, 1024,1024,32, 1024,1024,32,
        512,16,256,16,16,1};
    int b = blockIdx.x, t = 0, off = 0;
    for (;;) {
        int nb = (N[t] + 255) >> 8;
        if (b < nb) break;
        b -= nb; off += N[t]; ++t;
    }
    const void* src = a.p[t];
    const int n = N[t];
    const bool isf = detect_f32(src, n);
    const int i = b * 256 + threadIdx.x;
    if (i < n)
        dst[off + i] = isf ? ((const float*)src)[i] : bfb2f(((const u16*)src)[i]);
}

// ---------------- embeddings (thread per entity, fully unrolled MLPs) --------

__global__ __launch_bounds__(256) void k_path_embed(
    const float* __restrict__ traffic, const float* __restrict__ packets,
    const float* __restrict__ eq_lambda, const float* __restrict__ avg_pkts_lambda,
    const float* __restrict__ exp_max_factor, const float* __restrict__ pkts_lambda_on,
    const float* __restrict__ avg_t_off, const float* __restrict__ avg_t_on,
    const float* __restrict__ ar_a, const float* __restrict__ sigma,
    const int* __restrict__ model,
    const float* __restrict__ w1, const float* __restrict__ b1,
    const float* __restrict__ w2, const float* __restrict__ b2,
    float* __restrict__ path_state)
{
    int p = blockIdx.x * 256 + threadIdx.x;
    if (p >= P_) return;
    float f[10];
    f[0] = (traffic[p]        - 1385.4059f) * (1.f / 859.8119f);
    f[1] = (packets[p]        - 1.4015f)    * (1.f / 0.8933f);
    f[2] = (eq_lambda[p]      - 1350.9712f) * (1.f / 858.3162f);
    f[3] = (avg_pkts_lambda[p]- 0.9117f)    * (1.f / 0.9724f);
    f[4] = (exp_max_factor[p] - 6.6636f)    * (1.f / 4.7151f);
    f[5] = (pkts_lambda_on[p] - 0.9116f)    * (1.f / 1.6513f);
    f[6] = (avg_t_off[p]      - 1.6649f)    * (1.f / 2.3564f);
    f[7] = (avg_t_on[p]       - 1.6649f)    * (1.f / 2.3564f);
    f[8] = ar_a[p];
    f[9] = sigma[p];
    int mrow = 2 + model[p];
    float h1[32];
#pragma unroll
    for (int d = 0; d < 32; d++) {
        float a = b1[d] + w1[mrow * 32 + d];
        a += f[0] * w1[0 * 32 + d];
        a += f[1] * w1[1 * 32 + d];
#pragma unroll
        for (int j = 0; j < 8; j++) a += f[2 + j] * w1[(9 + j) * 32 + d];
        h1[d] = fmaxf(a, 0.f);
    }
#pragma unroll
    for (int d = 0; d < 32; d++) {
        float a = b2[d];
#pragma unroll
        for (int k = 0; k < 32; k++) a += h1[k] * w2[k * 32 + d];
        path_state[p * 32 + d] = fmaxf(a, 0.f);
    }
}

__global__ __launch_bounds__(256) void k_queue_embed(
    const float* __restrict__ queue_size, const float* __restrict__ weight,
    const int* __restrict__ priority,
    const float* __restrict__ w1, const float* __restrict__ b1,
    const float* __restrict__ w2, const float* __restrict__ b2,
    float* __restrict__ queue_state)
{
    int q = blockIdx.x * 256 + threadIdx.x;
    if (q >= NQ_) return;
    float f0 = (queue_size[q] - 30259.1055f) * (1.f / 21410.0957f);
    float f4 = weight[q];
    int prow = 1 + priority[q];
    float h1[32];
#pragma unroll
    for (int d = 0; d < 32; d++) {
        float a = b1[d] + w1[prow * 32 + d]
                + f0 * w1[0 * 32 + d] + f4 * w1[4 * 32 + d];
        h1[d] = fmaxf(a, 0.f);
    }
#pragma unroll
    for (int d = 0; d < 32; d++) {
        float a = b2[d];
#pragma unroll
        for (int k = 0; k < 32; k++) a += h1[k] * w2[k * 32 + d];
        queue_state[q * 32 + d] = fmaxf(a, 0.f);
    }
}

__global__ __launch_bounds__(256) void k_link_embed(
    const float* __restrict__ traffic, const float* __restrict__ capacity,
    const int* __restrict__ policy,
    const int* __restrict__ p2l, const int* __restrict__ p2l_deg,
    const float* __restrict__ w1, const float* __restrict__ b1,
    const float* __restrict__ w2, const float* __restrict__ b2,
    float* __restrict__ link_state)
{
    int l = blockIdx.x * 256 + threadIdx.x;
    if (l >= NL_) return;
    int deg = p2l_deg[l];
    float s = 0.f;
    for (int j = 0; j < deg; j++) s += traffic[p2l[l * 2 * P2L_ + 2 * j]];
    float load = s / capacity[l];
    int prow = 1 + policy[l];
    float h1[32];
#pragma unroll
    for (int d = 0; d < 32; d++) {
        float a = b1[d] + w1[prow * 32 + d] + load * w1[0 * 32 + d];
        h1[d] = fmaxf(a, 0.f);
    }
#pragma unroll
    for (int d = 0; d < 32; d++) {
        float a = b2[d];
#pragma unroll
        for (int k = 0; k < 32; k++) a += h1[k] * w2[k * 32 + d];
        link_state[l * 32 + d] = fmaxf(a, 0.f);
    }
}

// ---------------- z-prep: fold x@prW into per-entity tables ------------------
// zq[q] = prB + queue_state[q] @ prW[0:32];  zl[l] = link_state[l] @ prW[32:64]

__global__ __launch_bounds__(256) void k_zprep(
    const float* __restrict__ queue_state, const float* __restrict__ link_state,
    const float* __restrict__ prW, const float* __restrict__ prB,
    float* __restrict__ zq, float* __restrict__ zl)
{
    int e = blockIdx.x * 256 + threadIdx.x;
    if (e < NQ_) {
        float acc[32];
#pragma unroll
        for (int d = 0; d < 32; d++) acc[d] = prB[d];
#pragma unroll
        for (int k = 0; k < 32; k++) {
            float h = queue_state[e * 32 + k];
#pragma unroll
            for (int d = 0; d < 32; d++) acc[d] += h * prW[k * 32 + d];
        }
#pragma unroll
        for (int d = 0; d < 32; d++) zq[e * 32 + d] = acc[d];
    } else if (e < NQ_ + NL_) {
        int l = e - NQ_;
        float acc[32];
#pragma unroll
        for (int d = 0; d < 32; d++) acc[d] = 0.f;
#pragma unroll
        for (int k = 0; k < 32; k++) {
            float h = link_state[l * 32 + k];
#pragma unroll
            for (int d = 0; d < 32; d++) acc[d] += h * prW[(32 + k) * 32 + d];
        }
#pragma unroll
        for (int d = 0; d < 32; d++) zl[l * 32 + d] = acc[d];
    }
}

// ---------------- path RNN v2: lane = path, all state in registers -----------
// h_new = tanh(zq[q2p[p,t]] + zl[l2p[p,t]] + h @ prU); no LDS in hot loop.
// prU reads are wave-uniform (L1-resident 4 KB broadcast).

__global__ __launch_bounds__(256) void k_path_rnn(
    const int* __restrict__ q2p, const int* __restrict__ l2p,
    const int* __restrict__ length,
    const float* __restrict__ prU,
    const float* __restrict__ zq, const float* __restrict__ zl,
    float* __restrict__ path_state, u16* __restrict__ pss)
{
    const int p = blockIdx.x * 256 + threadIdx.x;
    const bool act = p < P_;
    const int pp = act ? p : 0;
    const int len = act ? length[pp] : 0;

    // hop indices for all 8 timesteps (coalesced int4 loads)
    int4 qi0 = *(const int4*)(q2p + (size_t)pp * 8);
    int4 qi1 = *(const int4*)(q2p + (size_t)pp * 8 + 4);
    int4 li0 = *(const int4*)(l2p + (size_t)pp * 8);
    int4 li1 = *(const int4*)(l2p + (size_t)pp * 8 + 4);
    int qidx[8] = {qi0.x, qi0.y, qi0.z, qi0.w, qi1.x, qi1.y, qi1.z, qi1.w};
    int lidx[8] = {li0.x, li0.y, li0.z, li0.w, li1.x, li1.y, li1.z, li1.w};

    float h[32];
#pragma unroll
    for (int j = 0; j < 8; j++)
        *(float4*)&h[4 * j] = *(const float4*)(path_state + (size_t)pp * 32 + 4 * j);

    // prefetch z for t=0
    float z[32];
#pragma unroll
    for (int j = 0; j < 8; j++) {
        float4 a = *(const float4*)(zq + (size_t)qidx[0] * 32 + 4 * j);
        float4 b = *(const float4*)(zl + (size_t)lidx[0] * 32 + 4 * j);
        a.x += b.x; a.y += b.y; a.z += b.z; a.w += b.w;
        *(float4*)&z[4 * j] = a;
    }

#pragma unroll 1
    for (int t = 0; t < 8; t++) {
        float acc[32];
#pragma unroll
        for (int d = 0; d < 32; d++) acc[d] = z[d];
        if (t < 7) {       // prefetch next timestep's z while matmul runs
            const int qn = qidx[t + 1], ln = lidx[t + 1];
#pragma unroll
            for (int j = 0; j < 8; j++) {
                float4 a = *(const float4*)(zq + (size_t)qn * 32 + 4 * j);
                float4 b = *(const float4*)(zl + (size_t)ln * 32 + 4 * j);
                a.x += b.x; a.y += b.y; a.z += b.z; a.w += b.w;
                *(float4*)&z[4 * j] = a;
            }
        }
#pragma unroll
        for (int k = 0; k < 32; k++) {
            const float hk = h[k];
#pragma unroll
            for (int j = 0; j < 8; j++) {
                const float4 u = *(const float4*)(prU + k * 32 + 4 * j);
                acc[4 * j + 0] += hk * u.x;
                acc[4 * j + 1] += hk * u.y;
                acc[4 * j + 2] += hk * u.z;
                acc[4 * j + 3] += hk * u.w;
            }
        }
        const bool m = (t < len);
#pragma unroll
        for (int d = 0; d < 32; d++) h[d] = m ? tanh_fast(acc[d]) : h[d];
        if (act) {
#pragma unroll
            for (int j = 0; j < 4; j++) {
                uint4 w;
                w.x = pk2(h[8 * j + 0], h[8 * j + 1]);
                w.y = pk2(h[8 * j + 2], h[8 * j + 3]);
                w.z = pk2(h[8 * j + 4], h[8 * j + 5]);
                w.w = pk2(h[8 * j + 6], h[8 * j + 7]);
                *(uint4*)(pss + (size_t)pp * 256 + t * 32 + 8 * j) = w;
            }
        }
    }
    if (act) {
#pragma unroll
        for (int j = 0; j < 8; j++)
            *(float4*)(path_state + (size_t)pp * 32 + 4 * j) = *(const float4*)&h[4 * j];
    }
}

// ---------------- queue update ----------------------------------------------

__global__ __launch_bounds__(256) void k_queue_update(
    const int* __restrict__ p2q, const int* __restrict__ p2q_deg,
    const float* __restrict__ qrW, const float* __restrict__ qrU,
    const float* __restrict__ qrB,
    const u16* __restrict__ pss, float* __restrict__ queue_state)
{
    __shared__ float wl[65 * 32];      // rows 0..31 qrW, 32..63 qrU, 64 = qrB
    __shared__ float xs[32][68];
    const int tid = threadIdx.x;
    for (int idx = tid; idx < 32 * 32; idx += 256) {
        wl[idx]           = qrW[idx];
        wl[32 * 32 + idx] = qrU[idx];
    }
    if (tid < 32) wl[64 * 32 + tid] = qrB[tid];
    __syncthreads();

    const int grp = tid >> 3, i = tid & 7;
    const int q = blockIdx.x * 32 + grp;
    if (q >= NQ_) return;
    const int deg = p2q_deg[q];
    float4 ps = {0.f, 0.f, 0.f, 0.f};
#pragma unroll 4
    for (int j = 0; j < deg; j++) {
        const int pj  = p2q[q * 2 * P2Q_ + 2 * j];
        int pos = p2q[q * 2 * P2Q_ + 2 * j + 1];
        int s = pos - 1; s = s < 0 ? 0 : (s > 7 ? 7 : s);
        const ushort4 v = *(const ushort4*)(pss + (size_t)pj * 256 + s * 32 + 4 * i);
        ps.x += bfb2f(v.x); ps.y += bfb2f(v.y);
        ps.z += bfb2f(v.z); ps.w += bfb2f(v.w);
    }
    const float4 qs = *(const float4*)(queue_state + (size_t)q * 32 + 4 * i);
    *(float4*)&xs[grp][4 * i]      = ps;
    *(float4*)&xs[grp][32 + 4 * i] = qs;

    float4 acc = *(const float4*)&wl[64 * 32 + 4 * i];
#pragma unroll
    for (int k = 0; k < 64; k += 4) {
        const float4 xv  = *(const float4*)&xs[grp][k];
        const float4 w0  = *(const float4*)&wl[(k + 0) * 32 + 4 * i];
        const float4 w1v = *(const float4*)&wl[(k + 1) * 32 + 4 * i];
        const float4 w2v = *(const float4*)&wl[(k + 2) * 32 + 4 * i];
        const float4 w3v = *(const float4*)&wl[(k + 3) * 32 + 4 * i];
        acc.x += xv.x * w0.x + xv.y * w1v.x + xv.z * w2v.x + xv.w * w3v.x;
        acc.y += xv.x * w0.y + xv.y * w1v.y + xv.z * w2v.y + xv.w * w3v.y;
        acc.z += xv.x * w0.z + xv.y * w1v.z + xv.z * w2v.z + xv.w * w3v.z;
        acc.w += xv.x * w0.w + xv.y * w1v.w + xv.z * w2v.w + xv.w * w3v.w;
    }
    float4 nh;
    nh.x = tanh_fast(acc.x); nh.y = tanh_fast(acc.y);
    nh.z = tanh_fast(acc.z); nh.w = tanh_fast(acc.w);
    *(float4*)(queue_state + (size_t)q * 32 + 4 * i) = nh;
}

// ---------------- link update ------------------------------------------------

__global__ __launch_bounds__(256) void k_link_update(
    const int* __restrict__ q2l,
    const float* __restrict__ lrW, const float* __restrict__ lrU,
    const float* __restrict__ lrB,
    const float* __restrict__ queue_state, float* __restrict__ link_state)
{
    __shared__ float wl[65 * 32];      // rows 0..31 lrW, 32..63 lrU, 64 = lrB
    __shared__ float xs[32][68];
    const int tid = threadIdx.x;
    for (int idx = tid; idx < 32 * 32; idx += 256) {
        wl[idx]           = lrW[idx];
        wl[32 * 32 + idx] = lrU[idx];
    }
    if (tid < 32) wl[64 * 32 + tid] = lrB[tid];
    __syncthreads();

    const int grp = tid >> 3, i = tid & 7;
    const int l = blockIdx.x * 32 + grp;
    if (l >= NL_) return;
    float4 h = *(const float4*)(link_state + (size_t)l * 32 + 4 * i);
#pragma unroll 1
    for (int t = 0; t < 3; t++) {
        const int qq = q2l[l * 3 + t];
        const float4 qg = *(const float4*)(queue_state + (size_t)qq * 32 + 4 * i);
        *(float4*)&xs[grp][4 * i]      = qg;
        *(float4*)&xs[grp][32 + 4 * i] = h;
        float4 acc = *(const float4*)&wl[64 * 32 + 4 * i];
#pragma unroll
        for (int k = 0; k < 64; k += 4) {
            const float4 xv  = *(const float4*)&xs[grp][k];
            const float4 w0  = *(const float4*)&wl[(k + 0) * 32 + 4 * i];
            const float4 w1v = *(const float4*)&wl[(k + 1) * 32 + 4 * i];
            const float4 w2v = *(const float4*)&wl[(k + 2) * 32 + 4 * i];
            const float4 w3v = *(const float4*)&wl[(k + 3) * 32 + 4 * i];
            acc.x += xv.x * w0.x + xv.y * w1v.x + xv.z * w2v.x + xv.w * w3v.x;
            acc.y += xv.x * w0.y + xv.y * w1v.y + xv.z * w2v.y + xv.w * w3v.y;
            acc.z += xv.x * w0.z + xv.y * w1v.z + xv.z * w2v.z + xv.w * w3v.z;
            acc.w += xv.x * w0.w + xv.y * w1v.w + xv.z * w2v.w + xv.w * w3v.w;
        }
        h.x = tanh_fast(acc.x); h.y = tanh_fast(acc.y);
        h.z = tanh_fast(acc.z); h.w = tanh_fast(acc.w);
    }
    *(float4*)(link_state + (size_t)l * 32 + 4 * i) = h;
}

// ---------------- readout: 8 lanes/path, lane owns 2 of 16 dims --------------

__global__ __launch_bounds__(256) void k_readout(
    const void* __restrict__ raw_traffic,
    const float* __restrict__ traffic, const float* __restrict__ packets,
    const float* __restrict__ capacity,
    const int* __restrict__ l2p, const int* __restrict__ length,
    const float* __restrict__ w1, const float* __restrict__ b1,
    const float* __restrict__ w2, const float* __restrict__ b2,
    const float* __restrict__ w3, const float* __restrict__ b3,
    const u16* __restrict__ pss, void* __restrict__ out)
{
    __shared__ float wl[817];   // w1[512] b1@512 w2@528 b2@784 w3@800 b3@816
    __shared__ float xs[32][52];
    const int tid = threadIdx.x;
    for (int idx = tid; idx < 512; idx += 256) wl[idx] = w1[idx];
    if (tid < 256) wl[528 + tid] = w2[tid];
    if (tid < 16) {
        wl[512 + tid] = b1[tid];
        wl[784 + tid] = b2[tid];
        wl[800 + tid] = w3[tid];
    }
    if (tid == 0) wl[816] = b3[0];
    __syncthreads();

    const int grp = tid >> 3, i = tid & 7;
    const int p = blockIdx.x * 32 + grp;
    if (p >= P_) return;
    const bool outf32 = detect_f32(raw_traffic, P_);   // output dtype follows inputs
    const int len = length[p];
    float qd = 0.f, ts = 0.f;
#pragma unroll 1
    for (int t = 0; t < 8; t++) {
        const ushort4 hu = *(const ushort4*)(pss + (size_t)p * 256 + t * 32 + 4 * i);
        float4 hv;
        hv.x = bfb2f(hu.x); hv.y = bfb2f(hu.y); hv.z = bfb2f(hu.z); hv.w = bfb2f(hu.w);
        *(float4*)&xs[grp][4 * i] = hv;
        float a0 = wl[512 + 2 * i], a1 = wl[512 + 2 * i + 1];
#pragma unroll
        for (int k = 0; k < 32; k += 4) {
            const float4 xv = *(const float4*)&xs[grp][k];
            const float2 u0 = *(const float2*)&wl[(k + 0) * 16 + 2 * i];
            const float2 u1 = *(const float2*)&wl[(k + 1) * 16 + 2 * i];
            const float2 u2 = *(const float2*)&wl[(k + 2) * 16 + 2 * i];
            const float2 u3 = *(const float2*)&wl[(k + 3) * 16 + 2 * i];
            a0 += xv.x * u0.x + xv.y * u1.x + xv.z * u2.x + xv.w * u3.x;
            a1 += xv.x * u0.y + xv.y * u1.y + xv.z * u2.y + xv.w * u3.y;
        }
        a0 = fmaxf(a0, 0.f); a1 = fmaxf(a1, 0.f);
        *(float2*)&xs[grp][32 + 2 * i] = make_float2(a0, a1);
        float c0 = wl[784 + 2 * i], c1 = wl[784 + 2 * i + 1];
#pragma unroll
        for (int k = 0; k < 16; k += 4) {
            const float4 xv = *(const float4*)&xs[grp][32 + k];
            const float2 u0 = *(const float2*)&wl[528 + (k + 0) * 16 + 2 * i];
            const float2 u1 = *(const float2*)&wl[528 + (k + 1) * 16 + 2 * i];
            const float2 u2 = *(const float2*)&wl[528 + (k + 2) * 16 + 2 * i];
            const float2 u3 = *(const float2*)&wl[528 + (k + 3) * 16 + 2 * i];
            c0 += xv.x * u0.x + xv.y * u1.x + xv.z * u2.x + xv.w * u3.x;
            c1 += xv.x * u0.y + xv.y * u1.y + xv.z * u2.y + xv.w * u3.y;
        }
        c0 = fmaxf(c0, 0.f); c1 = fmaxf(c1, 0.f);
        float pv = c0 * wl[800 + 2 * i] + c1 * wl[800 + 2 * i + 1];
        pv += __shfl_xor(pv, 1, 8);
        pv += __shfl_xor(pv, 2, 8);
        pv += __shfl_xor(pv, 4, 8);
        const float occv = pv + wl[816];
        if (t < len) {
            const float inv = 1.f / capacity[l2p[p * 8 + t]];
            qd += occv * inv;
            ts += inv;
        }
    }
    if (i == 0) {
        const float res = qd + (traffic[p] / packets[p]) * ts;
        if (outf32) ((float*)out)[p] = res;
        else        ((bf16*)out)[p] = __float2bfloat16(res);
    }
}

// ---------------- launcher ---------------------------------------------------

extern "C" void kernel_launch(void* const* d_in, const int* in_sizes, int n_in,
                              void* d_out, int out_size, void* d_ws, size_t ws_size,
                              hipStream_t stream)
{
    static const int CVT_N[40] = {
        50000,50000,50000,50000,50000,50000,50000,50000,50000,50000,
        2000,6000,6000,
        544,32,1024,32, 160,32,1024,32, 160,32,1024,32,
        2048,1024,32, 1024,1024,32, 1024,1024,32,
        512,16,256,16,16,1};

    const int*  length   = (const int*)d_in[13];
    const int*  model    = (const int*)d_in[14];
    const int*  policy   = (const int*)d_in[15];
    const int*  priority = (const int*)d_in[16];
    const int*  q2p      = (const int*)d_in[17];
    const int*  l2p      = (const int*)d_in[18];
    const int*  p2l      = (const int*)d_in[19];
    const int*  p2l_deg  = (const int*)d_in[20];
    const int*  p2q      = (const int*)d_in[21];
    const int*  p2q_deg  = (const int*)d_in[22];
    const int*  q2l      = (const int*)d_in[23];

    // float-tensor table: d_in[0..12] data, d_in[24..50] weights
    CvtArgs ca;
    for (int i = 0; i < 13; i++) ca.p[i] = d_in[i];
    for (int i = 0; i < 27; i++) ca.p[13 + i] = d_in[24 + i];

    int off[41]; off[0] = 0;
    for (int i = 0; i < 40; i++) off[i + 1] = off[i] + CVT_N[i];
    int nblk = 0;
    for (int i = 0; i < 40; i++) nblk += (CVT_N[i] + 255) / 256;

    float* ws = (float*)d_ws;
    const float* c_traffic    = ws + off[0];
    const float* c_packets    = ws + off[1];
    const float* c_eq_lambda  = ws + off[2];
    const float* c_apl        = ws + off[3];
    const float* c_emf        = ws + off[4];
    const float* c_plo        = ws + off[5];
    const float* c_atoff      = ws + off[6];
    const float* c_aton       = ws + off[7];
    const float* c_ar_a       = ws + off[8];
    const float* c_sigma      = ws + off[9];
    const float* c_capacity   = ws + off[10];
    const float* c_queue_size = ws + off[11];
    const float* c_weight     = ws + off[12];
    const float* c_pe_w1 = ws + off[13]; const float* c_pe_b1 = ws + off[14];
    const float* c_pe_w2 = ws + off[15]; const float* c_pe_b2 = ws + off[16];
    const float* c_le_w1 = ws + off[17]; const float* c_le_b1 = ws + off[18];
    const float* c_le_w2 = ws + off[19]; const float* c_le_b2 = ws + off[20];
    const float* c_qe_w1 = ws + off[21]; const float* c_qe_b1 = ws + off[22];
    const float* c_qe_w2 = ws + off[23]; const float* c_qe_b2 = ws + off[24];
    const float* c_prW = ws + off[25]; const float* c_prU = ws + off[26];
    const float* c_prB = ws + off[27];
    const float* c_qrW = ws + off[28]; const float* c_qrU = ws + off[29];
    const float* c_qrB = ws + off[30];
    const float* c_lrW = ws + off[31]; const float* c_lrU = ws + off[32];
    const float* c_lrB = ws + off[33];
    const float* c_ro_w1 = ws + off[34]; const float* c_ro_b1 = ws + off[35];
    const float* c_ro_w2 = ws + off[36]; const float* c_ro_b2 = ws + off[37];
    const float* c_ro_w3 = ws + off[38]; const float* c_ro_b3 = ws + off[39];

    size_t base = ((size_t)off[40] + 63) & ~(size_t)63;     // 526272 floats
    float* path_state  = ws + base;                          // P*32
    float* queue_state = path_state + (size_t)P_ * 32;       // NQ*32
    float* link_state  = queue_state + (size_t)NQ_ * 32;     // NL*32
    float* zq          = link_state + (size_t)NL_ * 32;      // NQ*32
    float* zl          = zq + (size_t)NQ_ * 32;              // NL*32
    u16*   pss         = (u16*)(zl + (size_t)NL_ * 32);      // P*256 bf16
    // total ws: ~10.6 MB (f32 region) + 25.6 MB (pss) = ~36.2 MB

    k_convert<<<nblk, 256, 0, stream>>>(ca, ws);

    k_path_embed<<<(P_ + 255) / 256, 256, 0, stream>>>(
        c_traffic, c_packets, c_eq_lambda, c_apl, c_emf, c_plo, c_atoff, c_aton,
        c_ar_a, c_sigma, model, c_pe_w1, c_pe_b1, c_pe_w2, c_pe_b2, path_state);
    k_queue_embed<<<(NQ_ + 255) / 256, 256, 0, stream>>>(
        c_queue_size, c_weight, priority, c_qe_w1, c_qe_b1, c_qe_w2, c_qe_b2,
        queue_state);
    k_link_embed<<<(NL_ + 255) / 256, 256, 0, stream>>>(
        c_traffic, c_capacity, policy, p2l, p2l_deg,
        c_le_w1, c_le_b1, c_le_w2, c_le_b2, link_state);

    for (int it = 0; it < ITERS_; ++it) {
        k_zprep<<<(NQ_ + NL_ + 255) / 256, 256, 0, stream>>>(
            queue_state, link_state, c_prW, c_prB, zq, zl);
        k_path_rnn<<<(P_ + 255) / 256, 256, 0, stream>>>(
            q2p, l2p, length, c_prU, zq, zl, path_state, pss);
        k_queue_update<<<(NQ_ + 31) / 32, 256, 0, stream>>>(
            p2q, p2q_deg, c_qrW, c_qrU, c_qrB, pss, queue_state);
        k_link_update<<<(NL_ + 31) / 32, 256, 0, stream>>>(
            q2l, c_lrW, c_lrU, c_lrB, queue_state, link_state);
    }

    k_readout<<<(P_ + 31) / 32, 256, 0, stream>>>(
        d_in[0], c_traffic, c_packets, c_capacity, l2p, length,
        c_ro_w1, c_ro_b1, c_ro_w2, c_ro_b2, c_ro_w3, c_ro_b3, pss, d_out);
}

// Round 5
// 804.213 us; speedup vs baseline: 3.0447x; 3.0447x over previous
//
#include <hip/hip_runtime.h>
#include <hip/hip_bf16.h>

#define P_ 50000
#define NL_ 2000
#define NQ_ 6000
#define L_ 8
#define P2L_ 128
#define P2Q_ 64
#define D_ 32
#define ITERS_ 8

typedef __hip_bfloat16 bf16;
typedef unsigned short u16;
typedef unsigned int u32;

__device__ __forceinline__ float bfb2f(u16 u) {
    union { u32 i; float f; } c; c.i = ((u32)u) << 16; return c.f;
}
__device__ __forceinline__ u16 f2bfb(float f) {
    union { bf16 h; u16 u; } c; c.h = __float2bfloat16(f); return c.u;
}
__device__ __forceinline__ u32 pk2(float a, float b) {
    return (u32)f2bfb(a) | ((u32)f2bfb(b) << 16);
}

__device__ __forceinline__ float tanh_fast(float x) {
    // exact identity tanh(x) = 1 - 2/(e^{2x}+1); safe at both saturations
    return 1.f - 2.f / (__expf(2.f * x) + 1.f);
}

// butterfly-order replicated state: hr[4s+c] = h[4*(i^s)+c] for this lane's i.
// Rebuilt from own 4 dims with 28 shfl_xor (all static register indices).
__device__ __forceinline__ void hr_rebuild(float* hr, float4 own) {
    hr[0] = own.x; hr[1] = own.y; hr[2] = own.z; hr[3] = own.w;
#pragma unroll
    for (int c = 0; c < 4; c++)  hr[4 + c]  = __shfl_xor(hr[c], 1, 64);
#pragma unroll
    for (int c = 0; c < 8; c++)  hr[8 + c]  = __shfl_xor(hr[c], 2, 64);
#pragma unroll
    for (int c = 0; c < 16; c++) hr[16 + c] = __shfl_xor(hr[c], 4, 64);
}

// acc[4] += full-h @ W[:, 4i..4i+3]; W rows in LDS, ub[s] = &W[(i^s)*4][4i]
__device__ __forceinline__ float4 matvec32(const float* hr,
                                           const float* const* ub, float4 acc) {
#pragma unroll
    for (int s = 0; s < 8; s++) {
#pragma unroll
        for (int c = 0; c < 4; c++) {
            const float4 u = *(const float4*)(ub[s] + 32 * c);
            const float hk = hr[4 * s + c];
            acc.x += hk * u.x; acc.y += hk * u.y;
            acc.z += hk * u.z; acc.w += hk * u.w;
        }
    }
    return acc;
}

// Runtime dtype probe: read up to 64 leading elements as bf16. Legit bf16 data
// is finite and in [1e-8,1e6] or exactly 0. f32 misread as bf16 puts random
// mantissa bits in exponent fields -> insane values; error prob ~1e-24.
__device__ bool detect_f32(const void* p, int n) {
    const u16* u = (const u16*)p;
    int m = n < 64 ? n : 64;
    bool bad = false;
    for (int k = 0; k < m; k++) {
        float v = bfb2f(u[k]);
        float av = fabsf(v);
        bool sane = (v == v) && (av <= 1e6f) && (av == 0.0f || av >= 1e-8f);
        bad |= !sane;
    }
    return bad;
}

// ---------------- input canonicalization: any-dtype -> f32 in ws -------------

struct CvtArgs { const void* p[40]; };

__global__ __launch_bounds__(256) void k_convert(CvtArgs a, float* __restrict__ dst) {
    static constexpr int N[40] = {
        50000,50000,50000,50000,50000,50000,50000,50000,50000,50000,
        2000,6000,6000,
        544,32,1024,32, 160,32,1024,32, 160,32,1024,32,
        2048,1024,32, 1024,1024,32, 1024,1024,32,
        512,16,256,16,16,1};
    int b = blockIdx.x, t = 0, off = 0;
    for (;;) {
        int nb = (N[t] + 255) >> 8;
        if (b < nb) break;
        b -= nb; off += N[t]; ++t;
    }
    const void* src = a.p[t];
    const int n = N[t];
    const bool isf = detect_f32(src, n);
    const int i = b * 256 + threadIdx.x;
    if (i < n)
        dst[off + i] = isf ? ((const float*)src)[i] : bfb2f(((const u16*)src)[i]);
}

// ---------------- embeddings (thread per entity, fully unrolled MLPs) --------

__global__ __launch_bounds__(256) void k_path_embed(
    const float* __restrict__ traffic, const float* __restrict__ packets,
    const float* __restrict__ eq_lambda, const float* __restrict__ avg_pkts_lambda,
    const float* __restrict__ exp_max_factor, const float* __restrict__ pkts_lambda_on,
    const float* __restrict__ avg_t_off, const float* __restrict__ avg_t_on,
    const float* __restrict__ ar_a, const float* __restrict__ sigma,
    const int* __restrict__ model,
    const float* __restrict__ w1, const float* __restrict__ b1,
    const float* __restrict__ w2, const float* __restrict__ b2,
    float* __restrict__ path_state)
{
    int p = blockIdx.x * 256 + threadIdx.x;
    if (p >= P_) return;
    float f[10];
    f[0] = (traffic[p]        - 1385.4059f) * (1.f / 859.8119f);
    f[1] = (packets[p]        - 1.4015f)    * (1.f / 0.8933f);
    f[2] = (eq_lambda[p]      - 1350.9712f) * (1.f / 858.3162f);
    f[3] = (avg_pkts_lambda[p]- 0.9117f)    * (1.f / 0.9724f);
    f[4] = (exp_max_factor[p] - 6.6636f)    * (1.f / 4.7151f);
    f[5] = (pkts_lambda_on[p] - 0.9116f)    * (1.f / 1.6513f);
    f[6] = (avg_t_off[p]      - 1.6649f)    * (1.f / 2.3564f);
    f[7] = (avg_t_on[p]       - 1.6649f)    * (1.f / 2.3564f);
    f[8] = ar_a[p];
    f[9] = sigma[p];
    int mrow = 2 + model[p];
    float h1[32];
#pragma unroll
    for (int d = 0; d < 32; d++) {
        float a = b1[d] + w1[mrow * 32 + d];
        a += f[0] * w1[0 * 32 + d];
        a += f[1] * w1[1 * 32 + d];
#pragma unroll
        for (int j = 0; j < 8; j++) a += f[2 + j] * w1[(9 + j) * 32 + d];
        h1[d] = fmaxf(a, 0.f);
    }
#pragma unroll
    for (int d = 0; d < 32; d++) {
        float a = b2[d];
#pragma unroll
        for (int k = 0; k < 32; k++) a += h1[k] * w2[k * 32 + d];
        path_state[p * 32 + d] = fmaxf(a, 0.f);
    }
}

__global__ __launch_bounds__(256) void k_queue_embed(
    const float* __restrict__ queue_size, const float* __restrict__ weight,
    const int* __restrict__ priority,
    const float* __restrict__ w1, const float* __restrict__ b1,
    const float* __restrict__ w2, const float* __restrict__ b2,
    float* __restrict__ queue_state)
{
    int q = blockIdx.x * 256 + threadIdx.x;
    if (q >= NQ_) return;
    float f0 = (queue_size[q] - 30259.1055f) * (1.f / 21410.0957f);
    float f4 = weight[q];
    int prow = 1 + priority[q];
    float h1[32];
#pragma unroll
    for (int d = 0; d < 32; d++) {
        float a = b1[d] + w1[prow * 32 + d]
                + f0 * w1[0 * 32 + d] + f4 * w1[4 * 32 + d];
        h1[d] = fmaxf(a, 0.f);
    }
#pragma unroll
    for (int d = 0; d < 32; d++) {
        float a = b2[d];
#pragma unroll
        for (int k = 0; k < 32; k++) a += h1[k] * w2[k * 32 + d];
        queue_state[q * 32 + d] = fmaxf(a, 0.f);
    }
}

__global__ __launch_bounds__(256) void k_link_embed(
    const float* __restrict__ traffic, const float* __restrict__ capacity,
    const int* __restrict__ policy,
    const int* __restrict__ p2l, const int* __restrict__ p2l_deg,
    const float* __restrict__ w1, const float* __restrict__ b1,
    const float* __restrict__ w2, const float* __restrict__ b2,
    float* __restrict__ link_state)
{
    int l = blockIdx.x * 256 + threadIdx.x;
    if (l >= NL_) return;
    int deg = p2l_deg[l];
    float s = 0.f;
    for (int j = 0; j < deg; j++) s += traffic[p2l[l * 2 * P2L_ + 2 * j]];
    float load = s / capacity[l];
    int prow = 1 + policy[l];
    float h1[32];
#pragma unroll
    for (int d = 0; d < 32; d++) {
        float a = b1[d] + w1[prow * 32 + d] + load * w1[0 * 32 + d];
        h1[d] = fmaxf(a, 0.f);
    }
#pragma unroll
    for (int d = 0; d < 32; d++) {
        float a = b2[d];
#pragma unroll
        for (int k = 0; k < 32; k++) a += h1[k] * w2[k * 32 + d];
        link_state[l * 32 + d] = fmaxf(a, 0.f);
    }
}

// ---------------- z-prep: 8 lanes/entity, butterfly-replicated state ---------
// zq[q] = prB + queue_state[q] @ prW[0:32];  zl[l] = link_state[l] @ prW[32:64]

__global__ __launch_bounds__(256) void k_zprep(
    const float* __restrict__ queue_state, const float* __restrict__ link_state,
    const float* __restrict__ prW, const float* __restrict__ prB,
    float* __restrict__ zq, float* __restrict__ zl)
{
    __shared__ float wq[32 * 32];
    __shared__ float wlk[32 * 32];
    __shared__ float bsh[32];
    const int tid = threadIdx.x;
#pragma unroll
    for (int j = 0; j < 4; j++) {
        wq[tid + 256 * j]  = prW[tid + 256 * j];
        wlk[tid + 256 * j] = prW[1024 + tid + 256 * j];
    }
    if (tid < 32) bsh[tid] = prB[tid];
    __syncthreads();

    const int grp = tid >> 3, i = tid & 7;
    const int e = blockIdx.x * 32 + grp;
    if (e >= NQ_ + NL_) return;
    const bool isq = e < NQ_;
    const float* st = isq ? (queue_state + (size_t)e * 32)
                          : (link_state + (size_t)(e - NQ_) * 32);
    const float* wbase = isq ? wq : wlk;
    const float* ub[8];
#pragma unroll
    for (int s = 0; s < 8; s++) ub[s] = wbase + (i ^ s) * 128 + 4 * i;

    float4 own = *(const float4*)(st + 4 * i);
    float hr[32];
    hr_rebuild(hr, own);

    float4 acc;
    if (isq) acc = *(const float4*)(bsh + 4 * i);
    else     acc = make_float4(0.f, 0.f, 0.f, 0.f);
    acc = matvec32(hr, ub, acc);

    float* dst = isq ? (zq + (size_t)e * 32) : (zl + (size_t)(e - NQ_) * 32);
    *(float4*)(dst + 4 * i) = acc;
}

// ---------------- path RNN v3: 8 lanes/path, 4 dims/lane ---------------------
// h = tanh(zq[q2p[p,t]] + zl[l2p[p,t]] + h @ prU); prU in LDS (conflict-free
// broadcast reads); h replicated per-lane in butterfly order; t fully unrolled.

__global__ __launch_bounds__(256) void k_path_rnn(
    const int* __restrict__ q2p, const int* __restrict__ l2p,
    const int* __restrict__ length,
    const float* __restrict__ prU,
    const float* __restrict__ zq, const float* __restrict__ zl,
    float* __restrict__ path_state, u16* __restrict__ pss)
{
    __shared__ float uw[32 * 32];
    const int tid = threadIdx.x;
#pragma unroll
    for (int j = 0; j < 4; j++) uw[tid + 256 * j] = prU[tid + 256 * j];
    __syncthreads();

    const int grp = tid >> 3, i = tid & 7;
    const int p = blockIdx.x * 32 + grp;
    if (p >= P_) return;
    const int len = length[p];

    const int4 qi0 = *(const int4*)(q2p + (size_t)p * 8);
    const int4 qi1 = *(const int4*)(q2p + (size_t)p * 8 + 4);
    const int4 li0 = *(const int4*)(l2p + (size_t)p * 8);
    const int4 li1 = *(const int4*)(l2p + (size_t)p * 8 + 4);
    const int qidx[8] = {qi0.x, qi0.y, qi0.z, qi0.w, qi1.x, qi1.y, qi1.z, qi1.w};
    const int lidx[8] = {li0.x, li0.y, li0.z, li0.w, li1.x, li1.y, li1.z, li1.w};

    const float* ub[8];
#pragma unroll
    for (int s = 0; s < 8; s++) ub[s] = uw + (i ^ s) * 128 + 4 * i;

    float4 own = *(const float4*)(path_state + (size_t)p * 32 + 4 * i);
    float hr[32];
    hr_rebuild(hr, own);

    float4 z;
    {
        const float4 a = *(const float4*)(zq + (size_t)qidx[0] * 32 + 4 * i);
        const float4 b = *(const float4*)(zl + (size_t)lidx[0] * 32 + 4 * i);
        z = make_float4(a.x + b.x, a.y + b.y, a.z + b.z, a.w + b.w);
    }

#pragma unroll
    for (int t = 0; t < 8; t++) {
        float4 acc = z;
        if (t < 7) {   // prefetch next z while the matvec runs (static idx)
            const float4 a = *(const float4*)(zq + (size_t)qidx[t + 1] * 32 + 4 * i);
            const float4 b = *(const float4*)(zl + (size_t)lidx[t + 1] * 32 + 4 * i);
            z = make_float4(a.x + b.x, a.y + b.y, a.z + b.z, a.w + b.w);
        }
        acc = matvec32(hr, ub, acc);
        const bool m = (t < len);
        own.x = m ? tanh_fast(acc.x) : own.x;
        own.y = m ? tanh_fast(acc.y) : own.y;
        own.z = m ? tanh_fast(acc.z) : own.z;
        own.w = m ? tanh_fast(acc.w) : own.w;
        uint2 w2;
        w2.x = pk2(own.x, own.y);
        w2.y = pk2(own.z, own.w);
        *(uint2*)(pss + (size_t)p * 256 + t * 32 + 4 * i) = w2;
        if (t < 7) hr_rebuild(hr, own);
    }
    *(float4*)(path_state + (size_t)p * 32 + 4 * i) = own;
}

// ---------------- queue update ----------------------------------------------

__global__ __launch_bounds__(256) void k_queue_update(
    const int* __restrict__ p2q, const int* __restrict__ p2q_deg,
    const float* __restrict__ qrW, const float* __restrict__ qrU,
    const float* __restrict__ qrB,
    const u16* __restrict__ pss, float* __restrict__ queue_state)
{
    __shared__ float wl[65 * 32];      // rows 0..31 qrW, 32..63 qrU, 64 = qrB
    __shared__ float xs[32][68];
    const int tid = threadIdx.x;
    for (int idx = tid; idx < 32 * 32; idx += 256) {
        wl[idx]           = qrW[idx];
        wl[32 * 32 + idx] = qrU[idx];
    }
    if (tid < 32) wl[64 * 32 + tid] = qrB[tid];
    __syncthreads();

    const int grp = tid >> 3, i = tid & 7;
    const int q = blockIdx.x * 32 + grp;
    if (q >= NQ_) return;
    const int deg = p2q_deg[q];
    float4 ps = {0.f, 0.f, 0.f, 0.f};
#pragma unroll 4
    for (int j = 0; j < deg; j++) {
        const int pj  = p2q[q * 2 * P2Q_ + 2 * j];
        int pos = p2q[q * 2 * P2Q_ + 2 * j + 1];
        int s = pos - 1; s = s < 0 ? 0 : (s > 7 ? 7 : s);
        const ushort4 v = *(const ushort4*)(pss + (size_t)pj * 256 + s * 32 + 4 * i);
        ps.x += bfb2f(v.x); ps.y += bfb2f(v.y);
        ps.z += bfb2f(v.z); ps.w += bfb2f(v.w);
    }
    const float4 qs = *(const float4*)(queue_state + (size_t)q * 32 + 4 * i);
    *(float4*)&xs[grp][4 * i]      = ps;
    *(float4*)&xs[grp][32 + 4 * i] = qs;

    float4 acc = *(const float4*)&wl[64 * 32 + 4 * i];
#pragma unroll
    for (int k = 0; k < 64; k += 4) {
        const float4 xv  = *(const float4*)&xs[grp][k];
        const float4 w0  = *(const float4*)&wl[(k + 0) * 32 + 4 * i];
        const float4 w1v = *(const float4*)&wl[(k + 1) * 32 + 4 * i];
        const float4 w2v = *(const float4*)&wl[(k + 2) * 32 + 4 * i];
        const float4 w3v = *(const float4*)&wl[(k + 3) * 32 + 4 * i];
        acc.x += xv.x * w0.x + xv.y * w1v.x + xv.z * w2v.x + xv.w * w3v.x;
        acc.y += xv.x * w0.y + xv.y * w1v.y + xv.z * w2v.y + xv.w * w3v.y;
        acc.z += xv.x * w0.z + xv.y * w1v.z + xv.z * w2v.z + xv.w * w3v.z;
        acc.w += xv.x * w0.w + xv.y * w1v.w + xv.z * w2v.w + xv.w * w3v.w;
    }
    float4 nh;
    nh.x = tanh_fast(acc.x); nh.y = tanh_fast(acc.y);
    nh.z = tanh_fast(acc.z); nh.w = tanh_fast(acc.w);
    *(float4*)(queue_state + (size_t)q * 32 + 4 * i) = nh;
}

// ---------------- link update ------------------------------------------------

__global__ __launch_bounds__(256) void k_link_update(
    const int* __restrict__ q2l,
    const float* __restrict__ lrW, const float* __restrict__ lrU,
    const float* __restrict__ lrB,
    const float* __restrict__ queue_state, float* __restrict__ link_state)
{
    __shared__ float wl[65 * 32];      // rows 0..31 lrW, 32..63 lrU, 64 = lrB
    __shared__ float xs[32][68];
    const int tid = threadIdx.x;
    for (int idx = tid; idx < 32 * 32; idx += 256) {
        wl[idx]           = lrW[idx];
        wl[32 * 32 + idx] = lrU[idx];
    }
    if (tid < 32) wl[64 * 32 + tid] = lrB[tid];
    __syncthreads();

    const int grp = tid >> 3, i = tid & 7;
    const int l = blockIdx.x * 32 + grp;
    if (l >= NL_) return;
    float4 h = *(const float4*)(link_state + (size_t)l * 32 + 4 * i);
#pragma unroll 1
    for (int t = 0; t < 3; t++) {
        const int qq = q2l[l * 3 + t];
        const float4 qg = *(const float4*)(queue_state + (size_t)qq * 32 + 4 * i);
        *(float4*)&xs[grp][4 * i]      = qg;
        *(float4*)&xs[grp][32 + 4 * i] = h;
        float4 acc = *(const float4*)&wl[64 * 32 + 4 * i];
#pragma unroll
        for (int k = 0; k < 64; k += 4) {
            const float4 xv  = *(const float4*)&xs[grp][k];
            const float4 w0  = *(const float4*)&wl[(k + 0) * 32 + 4 * i];
            const float4 w1v = *(const float4*)&wl[(k + 1) * 32 + 4 * i];
            const float4 w2v = *(const float4*)&wl[(k + 2) * 32 + 4 * i];
            const float4 w3v = *(const float4*)&wl[(k + 3) * 32 + 4 * i];
            acc.x += xv.x * w0.x + xv.y * w1v.x + xv.z * w2v.x + xv.w * w3v.x;
            acc.y += xv.x * w0.y + xv.y * w1v.y + xv.z * w2v.y + xv.w * w3v.y;
            acc.z += xv.x * w0.z + xv.y * w1v.z + xv.z * w2v.z + xv.w * w3v.z;
            acc.w += xv.x * w0.w + xv.y * w1v.w + xv.z * w2v.w + xv.w * w3v.w;
        }
        h.x = tanh_fast(acc.x); h.y = tanh_fast(acc.y);
        h.z = tanh_fast(acc.z); h.w = tanh_fast(acc.w);
    }
    *(float4*)(link_state + (size_t)l * 32 + 4 * i) = h;
}

// ---------------- readout: 8 lanes/path, lane owns 2 of 16 dims --------------

__global__ __launch_bounds__(256) void k_readout(
    const void* __restrict__ raw_traffic,
    const float* __restrict__ traffic, const float* __restrict__ packets,
    const float* __restrict__ capacity,
    const int* __restrict__ l2p, const int* __restrict__ length,
    const float* __restrict__ w1, const float* __restrict__ b1,
    const float* __restrict__ w2, const float* __restrict__ b2,
    const float* __restrict__ w3, const float* __restrict__ b3,
    const u16* __restrict__ pss, void* __restrict__ out)
{
    __shared__ float wl[817];   // w1[512] b1@512 w2@528 b2@784 w3@800 b3@816
    __shared__ float xs[32][52];
    const int tid = threadIdx.x;
    for (int idx = tid; idx < 512; idx += 256) wl[idx] = w1[idx];
    if (tid < 256) wl[528 + tid] = w2[tid];
    if (tid < 16) {
        wl[512 + tid] = b1[tid];
        wl[784 + tid] = b2[tid];
        wl[800 + tid] = w3[tid];
    }
    if (tid == 0) wl[816] = b3[0];
    __syncthreads();

    const int grp = tid >> 3, i = tid & 7;
    const int p = blockIdx.x * 32 + grp;
    if (p >= P_) return;
    const bool outf32 = detect_f32(raw_traffic, P_);   // output dtype follows inputs
    const int len = length[p];
    float qd = 0.f, ts = 0.f;
#pragma unroll 1
    for (int t = 0; t < 8; t++) {
        const ushort4 hu = *(const ushort4*)(pss + (size_t)p * 256 + t * 32 + 4 * i);
        float4 hv;
        hv.x = bfb2f(hu.x); hv.y = bfb2f(hu.y); hv.z = bfb2f(hu.z); hv.w = bfb2f(hu.w);
        *(float4*)&xs[grp][4 * i] = hv;
        float a0 = wl[512 + 2 * i], a1 = wl[512 + 2 * i + 1];
#pragma unroll
        for (int k = 0; k < 32; k += 4) {
            const float4 xv = *(const float4*)&xs[grp][k];
            const float2 u0 = *(const float2*)&wl[(k + 0) * 16 + 2 * i];
            const float2 u1 = *(const float2*)&wl[(k + 1) * 16 + 2 * i];
            const float2 u2 = *(const float2*)&wl[(k + 2) * 16 + 2 * i];
            const float2 u3 = *(const float2*)&wl[(k + 3) * 16 + 2 * i];
            a0 += xv.x * u0.x + xv.y * u1.x + xv.z * u2.x + xv.w * u3.x;
            a1 += xv.x * u0.y + xv.y * u1.y + xv.z * u2.y + xv.w * u3.y;
        }
        a0 = fmaxf(a0, 0.f); a1 = fmaxf(a1, 0.f);
        *(float2*)&xs[grp][32 + 2 * i] = make_float2(a0, a1);
        float c0 = wl[784 + 2 * i], c1 = wl[784 + 2 * i + 1];
#pragma unroll
        for (int k = 0; k < 16; k += 4) {
            const float4 xv = *(const float4*)&xs[grp][32 + k];
            const float2 u0 = *(const float2*)&wl[528 + (k + 0) * 16 + 2 * i];
            const float2 u1 = *(const float2*)&wl[528 + (k + 1) * 16 + 2 * i];
            const float2 u2 = *(const float2*)&wl[528 + (k + 2) * 16 + 2 * i];
            const float2 u3 = *(const float2*)&wl[528 + (k + 3) * 16 + 2 * i];
            c0 += xv.x * u0.x + xv.y * u1.x + xv.z * u2.x + xv.w * u3.x;
            c1 += xv.x * u0.y + xv.y * u1.y + xv.z * u2.y + xv.w * u3.y;
        }
        c0 = fmaxf(c0, 0.f); c1 = fmaxf(c1, 0.f);
        float pv = c0 * wl[800 + 2 * i] + c1 * wl[800 + 2 * i + 1];
        pv += __shfl_xor(pv, 1, 8);
        pv += __shfl_xor(pv, 2, 8);
        pv += __shfl_xor(pv, 4, 8);
        const float occv = pv + wl[816];
        if (t < len) {
            const float inv = 1.f / capacity[l2p[p * 8 + t]];
            qd += occv * inv;
            ts += inv;
        }
    }
    if (i == 0) {
        const float res = qd + (traffic[p] / packets[p]) * ts;
        if (outf32) ((float*)out)[p] = res;
        else        ((bf16*)out)[p] = __float2bfloat16(res);
    }
}

// ---------------- launcher ---------------------------------------------------

extern "C" void kernel_launch(void* const* d_in, const int* in_sizes, int n_in,
                              void* d_out, int out_size, void* d_ws, size_t ws_size,
                              hipStream_t stream)
{
    static const int CVT_N[40] = {
        50000,50000,50000,50000,50000,50000,50000,50000,50000,50000,
        2000,6000,6000,
        544,32,1024,32, 160,32,1024,32, 160,32,1024,32,
        2048,1024,32, 1024,1024,32, 1024,1024,32,
        512,16,256,16,16,1};

    const int*  length   = (const int*)d_in[13];
    const int*  model    = (const int*)d_in[14];
    const int*  policy   = (const int*)d_in[15];
    const int*  priority = (const int*)d_in[16];
    const int*  q2p      = (const int*)d_in[17];
    const int*  l2p      = (const int*)d_in[18];
    const int*  p2l      = (const int*)d_in[19];
    const int*  p2l_deg  = (const int*)d_in[20];
    const int*  p2q      = (const int*)d_in[21];
    const int*  p2q_deg  = (const int*)d_in[22];
    const int*  q2l      = (const int*)d_in[23];

    // float-tensor table: d_in[0..12] data, d_in[24..50] weights
    CvtArgs ca;
    for (int i = 0; i < 13; i++) ca.p[i] = d_in[i];
    for (int i = 0; i < 27; i++) ca.p[13 + i] = d_in[24 + i];

    int off[41]; off[0] = 0;
    for (int i = 0; i < 40; i++) off[i + 1] = off[i] + CVT_N[i];
    int nblk = 0;
    for (int i = 0; i < 40; i++) nblk += (CVT_N[i] + 255) / 256;

    float* ws = (float*)d_ws;
    const float* c_traffic    = ws + off[0];
    const float* c_packets    = ws + off[1];
    const float* c_eq_lambda  = ws + off[2];
    const float* c_apl        = ws + off[3];
    const float* c_emf        = ws + off[4];
    const float* c_plo        = ws + off[5];
    const float* c_atoff      = ws + off[6];
    const float* c_aton       = ws + off[7];
    const float* c_ar_a       = ws + off[8];
    const float* c_sigma      = ws + off[9];
    const float* c_capacity   = ws + off[10];
    const float* c_queue_size = ws + off[11];
    const float* c_weight     = ws + off[12];
    const float* c_pe_w1 = ws + off[13]; const float* c_pe_b1 = ws + off[14];
    const float* c_pe_w2 = ws + off[15]; const float* c_pe_b2 = ws + off[16];
    const float* c_le_w1 = ws + off[17]; const float* c_le_b1 = ws + off[18];
    const float* c_le_w2 = ws + off[19]; const float* c_le_b2 = ws + off[20];
    const float* c_qe_w1 = ws + off[21]; const float* c_qe_b1 = ws + off[22];
    const float* c_qe_w2 = ws + off[23]; const float* c_qe_b2 = ws + off[24];
    const float* c_prW = ws + off[25]; const float* c_prU = ws + off[26];
    const float* c_prB = ws + off[27];
    const float* c_qrW = ws + off[28]; const float* c_qrU = ws + off[29];
    const float* c_qrB = ws + off[30];
    const float* c_lrW = ws + off[31]; const float* c_lrU = ws + off[32];
    const float* c_lrB = ws + off[33];
    const float* c_ro_w1 = ws + off[34]; const float* c_ro_b1 = ws + off[35];
    const float* c_ro_w2 = ws + off[36]; const float* c_ro_b2 = ws + off[37];
    const float* c_ro_w3 = ws + off[38]; const float* c_ro_b3 = ws + off[39];

    size_t base = ((size_t)off[40] + 63) & ~(size_t)63;     // 526272 floats
    float* path_state  = ws + base;                          // P*32
    float* queue_state = path_state + (size_t)P_ * 32;       // NQ*32
    float* link_state  = queue_state + (size_t)NQ_ * 32;     // NL*32
    float* zq          = link_state + (size_t)NL_ * 32;      // NQ*32
    float* zl          = zq + (size_t)NQ_ * 32;              // NL*32
    u16*   pss         = (u16*)(zl + (size_t)NL_ * 32);      // P*256 bf16
    // total ws: ~10.6 MB (f32 region) + 25.6 MB (pss) = ~36.2 MB

    k_convert<<<nblk, 256, 0, stream>>>(ca, ws);

    k_path_embed<<<(P_ + 255) / 256, 256, 0, stream>>>(
        c_traffic, c_packets, c_eq_lambda, c_apl, c_emf, c_plo, c_atoff, c_aton,
        c_ar_a, c_sigma, model, c_pe_w1, c_pe_b1, c_pe_w2, c_pe_b2, path_state);
    k_queue_embed<<<(NQ_ + 255) / 256, 256, 0, stream>>>(
        c_queue_size, c_weight, priority, c_qe_w1, c_qe_b1, c_qe_w2, c_qe_b2,
        queue_state);
    k_link_embed<<<(NL_ + 255) / 256, 256, 0, stream>>>(
        c_traffic, c_capacity, policy, p2l, p2l_deg,
        c_le_w1, c_le_b1, c_le_w2, c_le_b2, link_state);

    for (int it = 0; it < ITERS_; ++it) {
        k_zprep<<<(NQ_ + NL_ + 31) / 32, 256, 0, stream>>>(
            queue_state, link_state, c_prW, c_prB, zq, zl);
        k_path_rnn<<<(P_ + 31) / 32, 256, 0, stream>>>(
            q2p, l2p, length, c_prU, zq, zl, path_state, pss);
        k_queue_update<<<(NQ_ + 31) / 32, 256, 0, stream>>>(
            p2q, p2q_deg, c_qrW, c_qrU, c_qrB, pss, queue_state);
        k_link_update<<<(NL_ + 31) / 32, 256, 0, stream>>>(
            q2l, c_lrW, c_lrU, c_lrB, queue_state, link_state);
    }

    k_readout<<<(P_ + 31) / 32, 256, 0, stream>>>(
        d_in[0], c_traffic, c_packets, c_capacity, l2p, length,
        c_ro_w1, c_ro_b1, c_ro_w2, c_ro_b2, c_ro_w3, c_ro_b3, pss, d_out);
}

// Round 6
// 724.729 us; speedup vs baseline: 3.3786x; 1.1097x over previous
//
#include <hip/hip_runtime.h>
#include <hip/hip_bf16.h>

#define P_ 50000
#define NL_ 2000
#define NQ_ 6000
#define L_ 8
#define P2L_ 128
#define P2Q_ 64
#define D_ 32
#define ITERS_ 8

typedef __hip_bfloat16 bf16;
typedef unsigned short u16;
typedef unsigned int u32;

__device__ __forceinline__ float bfb2f(u16 u) {
    union { u32 i; float f; } c; c.i = ((u32)u) << 16; return c.f;
}
__device__ __forceinline__ u16 f2bfb(float f) {
    union { bf16 h; u16 u; } c; c.h = __float2bfloat16(f); return c.u;
}
__device__ __forceinline__ u32 pk2(float a, float b) {
    return (u32)f2bfb(a) | ((u32)f2bfb(b) << 16);
}

__device__ __forceinline__ float tanh_fast(float x) {
    // exact identity tanh(x) = 1 - 2/(e^{2x}+1); safe at both saturations
    return 1.f - 2.f / (__expf(2.f * x) + 1.f);
}

// butterfly-order replicated state: hr[4s+c] = h[4*(i^s)+c] for this lane's i.
// Rebuilt from own 4 dims with 28 shfl_xor (all static register indices).
__device__ __forceinline__ void hr_rebuild(float* hr, float4 own) {
    hr[0] = own.x; hr[1] = own.y; hr[2] = own.z; hr[3] = own.w;
#pragma unroll
    for (int c = 0; c < 4; c++)  hr[4 + c]  = __shfl_xor(hr[c], 1, 64);
#pragma unroll
    for (int c = 0; c < 8; c++)  hr[8 + c]  = __shfl_xor(hr[c], 2, 64);
#pragma unroll
    for (int c = 0; c < 16; c++) hr[16 + c] = __shfl_xor(hr[c], 4, 64);
}

// acc[4] += full-h @ W[:, 4i..4i+3]; W rows in LDS, ub[s] = &W[(i^s)*4][4i]
__device__ __forceinline__ float4 matvec32(const float* hr,
                                           const float* const* ub, float4 acc) {
#pragma unroll
    for (int s = 0; s < 8; s++) {
#pragma unroll
        for (int c = 0; c < 4; c++) {
            const float4 u = *(const float4*)(ub[s] + 32 * c);
            const float hk = hr[4 * s + c];
            acc.x += hk * u.x; acc.y += hk * u.y;
            acc.z += hk * u.z; acc.w += hk * u.w;
        }
    }
    return acc;
}

// Runtime dtype probe: read up to 64 leading elements as bf16. Legit bf16 data
// is finite and in [1e-8,1e6] or exactly 0. f32 misread as bf16 puts random
// mantissa bits in exponent fields -> insane values; error prob ~1e-24.
__device__ bool detect_f32(const void* p, int n) {
    const u16* u = (const u16*)p;
    int m = n < 64 ? n : 64;
    bool bad = false;
    for (int k = 0; k < m; k++) {
        float v = bfb2f(u[k]);
        float av = fabsf(v);
        bool sane = (v == v) && (av <= 1e6f) && (av == 0.0f || av >= 1e-8f);
        bad |= !sane;
    }
    return bad;
}

// ---------------- input canonicalization: any-dtype -> f32 in ws -------------

struct CvtArgs { const void* p[40]; };

__global__ __launch_bounds__(256) void k_convert(CvtArgs a, float* __restrict__ dst) {
    static constexpr int N[40] = {
        50000,50000,50000,50000,50000,50000,50000,50000,50000,50000,
        2000,6000,6000,
        544,32,1024,32, 160,32,1024,32, 160,32,1024,32,
        2048,1024,32, 1024,1024,32, 1024,1024,32,
        512,16,256,16,16,1};
    int b = blockIdx.x, t = 0, off = 0;
    for (;;) {
        int nb = (N[t] + 255) >> 8;
        if (b < nb) break;
        b -= nb; off += N[t]; ++t;
    }
    const void* src = a.p[t];
    const int n = N[t];
    const bool isf = detect_f32(src, n);
    const int i = b * 256 + threadIdx.x;
    if (i < n)
        dst[off + i] = isf ? ((const float*)src)[i] : bfb2f(((const u16*)src)[i]);
}

// ---------------- embeddings ------------------------------------------------

__global__ __launch_bounds__(256) void k_path_embed(
    const float* __restrict__ traffic, const float* __restrict__ packets,
    const float* __restrict__ eq_lambda, const float* __restrict__ avg_pkts_lambda,
    const float* __restrict__ exp_max_factor, const float* __restrict__ pkts_lambda_on,
    const float* __restrict__ avg_t_off, const float* __restrict__ avg_t_on,
    const float* __restrict__ ar_a, const float* __restrict__ sigma,
    const int* __restrict__ model,
    const float* __restrict__ w1, const float* __restrict__ b1,
    const float* __restrict__ w2, const float* __restrict__ b2,
    float* __restrict__ path_state)
{
    int p = blockIdx.x * 256 + threadIdx.x;
    if (p >= P_) return;
    float f[10];
    f[0] = (traffic[p]        - 1385.4059f) * (1.f / 859.8119f);
    f[1] = (packets[p]        - 1.4015f)    * (1.f / 0.8933f);
    f[2] = (eq_lambda[p]      - 1350.9712f) * (1.f / 858.3162f);
    f[3] = (avg_pkts_lambda[p]- 0.9117f)    * (1.f / 0.9724f);
    f[4] = (exp_max_factor[p] - 6.6636f)    * (1.f / 4.7151f);
    f[5] = (pkts_lambda_on[p] - 0.9116f)    * (1.f / 1.6513f);
    f[6] = (avg_t_off[p]      - 1.6649f)    * (1.f / 2.3564f);
    f[7] = (avg_t_on[p]       - 1.6649f)    * (1.f / 2.3564f);
    f[8] = ar_a[p];
    f[9] = sigma[p];
    int mrow = 2 + model[p];
    float h1[32];
#pragma unroll
    for (int d = 0; d < 32; d++) {
        float a = b1[d] + w1[mrow * 32 + d];
        a += f[0] * w1[0 * 32 + d];
        a += f[1] * w1[1 * 32 + d];
#pragma unroll
        for (int j = 0; j < 8; j++) a += f[2 + j] * w1[(9 + j) * 32 + d];
        h1[d] = fmaxf(a, 0.f);
    }
#pragma unroll
    for (int d = 0; d < 32; d++) {
        float a = b2[d];
#pragma unroll
        for (int k = 0; k < 32; k++) a += h1[k] * w2[k * 32 + d];
        path_state[p * 32 + d] = fmaxf(a, 0.f);
    }
}

__global__ __launch_bounds__(256) void k_queue_embed(
    const float* __restrict__ queue_size, const float* __restrict__ weight,
    const int* __restrict__ priority,
    const float* __restrict__ w1, const float* __restrict__ b1,
    const float* __restrict__ w2, const float* __restrict__ b2,
    float* __restrict__ queue_state)
{
    int q = blockIdx.x * 256 + threadIdx.x;
    if (q >= NQ_) return;
    float f0 = (queue_size[q] - 30259.1055f) * (1.f / 21410.0957f);
    float f4 = weight[q];
    int prow = 1 + priority[q];
    float h1[32];
#pragma unroll
    for (int d = 0; d < 32; d++) {
        float a = b1[d] + w1[prow * 32 + d]
                + f0 * w1[0 * 32 + d] + f4 * w1[4 * 32 + d];
        h1[d] = fmaxf(a, 0.f);
    }
#pragma unroll
    for (int d = 0; d < 32; d++) {
        float a = b2[d];
#pragma unroll
        for (int k = 0; k < 32; k++) a += h1[k] * w2[k * 32 + d];
        queue_state[q * 32 + d] = fmaxf(a, 0.f);
    }
}

// wave-per-link: 64 lanes split the <=128 traffic gathers, shfl reduce,
// then lanes 0..31 run the 2-layer MLP from LDS weights (broadcast reads).
__global__ __launch_bounds__(256) void k_link_embed(
    const float* __restrict__ traffic, const float* __restrict__ capacity,
    const int* __restrict__ policy,
    const int* __restrict__ p2l, const int* __restrict__ p2l_deg,
    const float* __restrict__ w1, const float* __restrict__ b1,
    const float* __restrict__ w2, const float* __restrict__ b2,
    float* __restrict__ link_state)
{
    __shared__ float wsh[1248];     // w1[160] b1@160 w2@192 b2@1216
    __shared__ float h1s[4][32];
    const int tid = threadIdx.x;
    if (tid < 160) wsh[tid] = w1[tid];
    if (tid < 32)  wsh[160 + tid] = b1[tid];
    for (int idx = tid; idx < 1024; idx += 256) wsh[192 + idx] = w2[idx];
    if (tid >= 32 && tid < 64) wsh[1216 + tid - 32] = b2[tid - 32];
    __syncthreads();

    const int w = tid >> 6, lane = tid & 63;
    const int l = blockIdx.x * 4 + w;          // grid = 500 exact
    const int deg = p2l_deg[l];
    float s = 0.f;
    if (lane < deg)      s += traffic[p2l[l * 256 + 2 * lane]];
    if (lane + 64 < deg) s += traffic[p2l[l * 256 + 2 * (lane + 64)]];
#pragma unroll
    for (int m = 1; m < 64; m <<= 1) s += __shfl_xor(s, m, 64);
    const float load = s / capacity[l];
    const int prow = 1 + policy[l];
    if (lane < 32) {
        float a = wsh[160 + lane] + wsh[prow * 32 + lane] + load * wsh[lane];
        h1s[w][lane] = fmaxf(a, 0.f);
    }
    __syncthreads();
    if (lane < 32) {
        float a = wsh[1216 + lane];
#pragma unroll
        for (int k = 0; k < 32; k++) a += h1s[w][k] * wsh[192 + k * 32 + lane];
        link_state[l * 32 + lane] = fmaxf(a, 0.f);
    }
}

// ---------------- z-prep (pre-loop only): fold x@prW into tables -------------
// zq[q] = prB + queue_state[q] @ prW[0:32];  zl[l] = link_state[l] @ prW[32:64]

__global__ __launch_bounds__(256) void k_zprep(
    const float* __restrict__ queue_state, const float* __restrict__ link_state,
    const float* __restrict__ prW, const float* __restrict__ prB,
    float* __restrict__ zq, float* __restrict__ zl)
{
    __shared__ float wq[32 * 32];
    __shared__ float wlk[32 * 32];
    __shared__ float bsh[32];
    const int tid = threadIdx.x;
#pragma unroll
    for (int j = 0; j < 4; j++) {
        wq[tid + 256 * j]  = prW[tid + 256 * j];
        wlk[tid + 256 * j] = prW[1024 + tid + 256 * j];
    }
    if (tid < 32) bsh[tid] = prB[tid];
    __syncthreads();

    const int grp = tid >> 3, i = tid & 7;
    const int e = blockIdx.x * 32 + grp;
    if (e >= NQ_ + NL_) return;
    const bool isq = e < NQ_;
    const float* st = isq ? (queue_state + (size_t)e * 32)
                          : (link_state + (size_t)(e - NQ_) * 32);
    const float* wbase = isq ? wq : wlk;
    const float* ub[8];
#pragma unroll
    for (int s = 0; s < 8; s++) ub[s] = wbase + (i ^ s) * 128 + 4 * i;

    float4 own = *(const float4*)(st + 4 * i);
    float hr[32];
    hr_rebuild(hr, own);

    float4 acc;
    if (isq) acc = *(const float4*)(bsh + 4 * i);
    else     acc = make_float4(0.f, 0.f, 0.f, 0.f);
    acc = matvec32(hr, ub, acc);

    float* dst = isq ? (zq + (size_t)e * 32) : (zl + (size_t)(e - NQ_) * 32);
    *(float4*)(dst + 4 * i) = acc;
}

// ---------------- path RNN v4: weights in registers (butterfly order) --------
// h = tanh(zq[q2p[p,t]] + zl[l2p[p,t]] + h @ prU); zero LDS in the hot loop.
// Ub[4s+c] = prU[4*(i^s)+c][4i..4i+3] -> matvec is 32 static-index float4 FMAs.

__global__ __launch_bounds__(256, 2) void k_path_rnn(
    const int* __restrict__ q2p, const int* __restrict__ l2p,
    const int* __restrict__ length,
    const float* __restrict__ prU,
    const float* __restrict__ zq, const float* __restrict__ zl,
    float* __restrict__ path_state, u16* __restrict__ pss)
{
    const int tid = threadIdx.x;
    const int grp = tid >> 3, i = tid & 7;
    const int p = blockIdx.x * 32 + grp;
    if (p >= P_) return;
    const int len = length[p];

    float4 Ub[32];
#pragma unroll
    for (int s = 0; s < 8; s++) {
        const float* rb = prU + ((i ^ s) * 128 + 4 * i);
#pragma unroll
        for (int c = 0; c < 4; c++)
            Ub[4 * s + c] = *(const float4*)(rb + 32 * c);
    }

    const int4 qi0 = *(const int4*)(q2p + (size_t)p * 8);
    const int4 qi1 = *(const int4*)(q2p + (size_t)p * 8 + 4);
    const int4 li0 = *(const int4*)(l2p + (size_t)p * 8);
    const int4 li1 = *(const int4*)(l2p + (size_t)p * 8 + 4);
    const int qidx[8] = {qi0.x, qi0.y, qi0.z, qi0.w, qi1.x, qi1.y, qi1.z, qi1.w};
    const int lidx[8] = {li0.x, li0.y, li0.z, li0.w, li1.x, li1.y, li1.z, li1.w};

    float4 own = *(const float4*)(path_state + (size_t)p * 32 + 4 * i);
    float hr[32];
    hr_rebuild(hr, own);

    float4 z;
    {
        const float4 a = *(const float4*)(zq + (size_t)qidx[0] * 32 + 4 * i);
        const float4 b = *(const float4*)(zl + (size_t)lidx[0] * 32 + 4 * i);
        z = make_float4(a.x + b.x, a.y + b.y, a.z + b.z, a.w + b.w);
    }

#pragma unroll
    for (int t = 0; t < 8; t++) {
        float4 acc = z;
        if (t < 7) {   // prefetch next z during the matvec (static idx)
            const float4 a = *(const float4*)(zq + (size_t)qidx[t + 1] * 32 + 4 * i);
            const float4 b = *(const float4*)(zl + (size_t)lidx[t + 1] * 32 + 4 * i);
            z = make_float4(a.x + b.x, a.y + b.y, a.z + b.z, a.w + b.w);
        }
#pragma unroll
        for (int k = 0; k < 32; k++) {
            const float hk = hr[k];
            acc.x += hk * Ub[k].x; acc.y += hk * Ub[k].y;
            acc.z += hk * Ub[k].z; acc.w += hk * Ub[k].w;
        }
        const bool m = (t < len);
        own.x = m ? tanh_fast(acc.x) : own.x;
        own.y = m ? tanh_fast(acc.y) : own.y;
        own.z = m ? tanh_fast(acc.z) : own.z;
        own.w = m ? tanh_fast(acc.w) : own.w;
        uint2 w2;
        w2.x = pk2(own.x, own.y);
        w2.y = pk2(own.z, own.w);
        *(uint2*)(pss + (size_t)p * 256 + t * 32 + 4 * i) = w2;
        if (t < 7) hr_rebuild(hr, own);
    }
    *(float4*)(path_state + (size_t)p * 32 + 4 * i) = own;
}

// ---------------- queue update v2: wave per queue, fused zq epilogue ---------
// 8 lane-groups split the deg-gather; 12-shfl cross-group reduce; redundant
// butterfly matvec per group; g==0 writes.

__global__ __launch_bounds__(256) void k_queue_update(
    const int* __restrict__ p2q, const int* __restrict__ p2q_deg,
    const float* __restrict__ qrW, const float* __restrict__ qrU,
    const float* __restrict__ qrB,
    const float* __restrict__ prWq, const float* __restrict__ prB,
    const u16* __restrict__ pss, float* __restrict__ queue_state,
    float* __restrict__ zq)
{
    __shared__ float wl[3 * 1024 + 64]; // qrW@0 qrU@1024 prWq@2048 qrB@3072 prB@3104
    const int tid = threadIdx.x;
#pragma unroll
    for (int j = 0; j < 4; j++) {
        wl[tid + 256 * j]        = qrW[tid + 256 * j];
        wl[1024 + tid + 256 * j] = qrU[tid + 256 * j];
        wl[2048 + tid + 256 * j] = prWq[tid + 256 * j];
    }
    if (tid < 32) { wl[3072 + tid] = qrB[tid]; wl[3104 + tid] = prB[tid]; }
    __syncthreads();

    const int w = tid >> 6, lane = tid & 63;
    const int g = lane >> 3, i = lane & 7;
    const int q = blockIdx.x * 4 + w;          // grid = 1500 exact
    const int deg = p2q_deg[q];

    float4 ps = {0.f, 0.f, 0.f, 0.f};
    for (int j = g; j < deg; j += 8) {
        const int pj = p2q[q * 128 + 2 * j];
        int pos = p2q[q * 128 + 2 * j + 1] - 1;
        pos = pos < 0 ? 0 : (pos > 7 ? 7 : pos);
        const ushort4 v = *(const ushort4*)(pss + (size_t)pj * 256 + pos * 32 + 4 * i);
        ps.x += bfb2f(v.x); ps.y += bfb2f(v.y);
        ps.z += bfb2f(v.z); ps.w += bfb2f(v.w);
    }
#pragma unroll
    for (int m = 8; m < 64; m <<= 1) {
        ps.x += __shfl_xor(ps.x, m, 64);
        ps.y += __shfl_xor(ps.y, m, 64);
        ps.z += __shfl_xor(ps.z, m, 64);
        ps.w += __shfl_xor(ps.w, m, 64);
    }
    const float4 qs = *(const float4*)(queue_state + (size_t)q * 32 + 4 * i);

    const float* ubW[8]; const float* ubU[8]; const float* ubP[8];
#pragma unroll
    for (int s = 0; s < 8; s++) {
        const int o = (i ^ s) * 128 + 4 * i;
        ubW[s] = wl + o; ubU[s] = wl + 1024 + o; ubP[s] = wl + 2048 + o;
    }

    float psr[32]; hr_rebuild(psr, ps);
    float qsr[32]; hr_rebuild(qsr, qs);
    float4 acc = *(const float4*)(wl + 3072 + 4 * i);
    acc = matvec32(psr, ubW, acc);
    acc = matvec32(qsr, ubU, acc);
    float4 nh;
    nh.x = tanh_fast(acc.x); nh.y = tanh_fast(acc.y);
    nh.z = tanh_fast(acc.z); nh.w = tanh_fast(acc.w);

    float nhr[32]; hr_rebuild(nhr, nh);
    float4 zacc = *(const float4*)(wl + 3104 + 4 * i);
    zacc = matvec32(nhr, ubP, zacc);

    if (g == 0) {
        *(float4*)(queue_state + (size_t)q * 32 + 4 * i) = nh;
        *(float4*)(zq + (size_t)q * 32 + 4 * i) = zacc;
    }
}

// ---------------- link update v2: wave per link, fused zl epilogue -----------

__global__ __launch_bounds__(256) void k_link_update(
    const int* __restrict__ q2l,
    const float* __restrict__ lrW, const float* __restrict__ lrU,
    const float* __restrict__ lrB,
    const float* __restrict__ prWl,
    const float* __restrict__ queue_state, float* __restrict__ link_state,
    float* __restrict__ zl)
{
    __shared__ float wl[3 * 1024 + 32]; // lrW@0 lrU@1024 prWl@2048 lrB@3072
    const int tid = threadIdx.x;
#pragma unroll
    for (int j = 0; j < 4; j++) {
        wl[tid + 256 * j]        = lrW[tid + 256 * j];
        wl[1024 + tid + 256 * j] = lrU[tid + 256 * j];
        wl[2048 + tid + 256 * j] = prWl[tid + 256 * j];
    }
    if (tid < 32) wl[3072 + tid] = lrB[tid];
    __syncthreads();

    const int w = tid >> 6, lane = tid & 63;
    const int i = lane & 7, g = lane >> 3;
    const int l = blockIdx.x * 4 + w;          // grid = 500 exact

    const float* ubW[8]; const float* ubU[8]; const float* ubP[8];
#pragma unroll
    for (int s = 0; s < 8; s++) {
        const int o = (i ^ s) * 128 + 4 * i;
        ubW[s] = wl + o; ubU[s] = wl + 1024 + o; ubP[s] = wl + 2048 + o;
    }

    float4 h = *(const float4*)(link_state + (size_t)l * 32 + 4 * i);
    float hhr[32]; hr_rebuild(hhr, h);

#pragma unroll
    for (int t = 0; t < 3; t++) {
        const int qq = q2l[l * 3 + t];
        const float4 qg = *(const float4*)(queue_state + (size_t)qq * 32 + 4 * i);
        float qgr[32]; hr_rebuild(qgr, qg);
        float4 acc = *(const float4*)(wl + 3072 + 4 * i);
        acc = matvec32(qgr, ubW, acc);
        acc = matvec32(hhr, ubU, acc);
        h.x = tanh_fast(acc.x); h.y = tanh_fast(acc.y);
        h.z = tanh_fast(acc.z); h.w = tanh_fast(acc.w);
        hr_rebuild(hhr, h);
    }
    float4 zacc = make_float4(0.f, 0.f, 0.f, 0.f);
    zacc = matvec32(hhr, ubP, zacc);

    if (g == 0) {
        *(float4*)(link_state + (size_t)l * 32 + 4 * i) = h;
        *(float4*)(zl + (size_t)l * 32 + 4 * i) = zacc;
    }
}

// ---------------- readout: 8 lanes/path, lane owns 2 of 16 dims --------------

__global__ __launch_bounds__(256) void k_readout(
    const void* __restrict__ raw_traffic,
    const float* __restrict__ traffic, const float* __restrict__ packets,
    const float* __restrict__ capacity,
    const int* __restrict__ l2p, const int* __restrict__ length,
    const float* __restrict__ w1, const float* __restrict__ b1,
    const float* __restrict__ w2, const float* __restrict__ b2,
    const float* __restrict__ w3, const float* __restrict__ b3,
    const u16* __restrict__ pss, void* __restrict__ out)
{
    __shared__ float wl[817];   // w1[512] b1@512 w2@528 b2@784 w3@800 b3@816
    __shared__ float xs[32][52];
    const int tid = threadIdx.x;
    for (int idx = tid; idx < 512; idx += 256) wl[idx] = w1[idx];
    if (tid < 256) wl[528 + tid] = w2[tid];
    if (tid < 16) {
        wl[512 + tid] = b1[tid];
        wl[784 + tid] = b2[tid];
        wl[800 + tid] = w3[tid];
    }
    if (tid == 0) wl[816] = b3[0];
    __syncthreads();

    const int grp = tid >> 3, i = tid & 7;
    const int p = blockIdx.x * 32 + grp;
    if (p >= P_) return;
    const bool outf32 = detect_f32(raw_traffic, P_);   // output dtype follows inputs
    const int len = length[p];
    float qd = 0.f, ts = 0.f;
#pragma unroll 1
    for (int t = 0; t < 8; t++) {
        const ushort4 hu = *(const ushort4*)(pss + (size_t)p * 256 + t * 32 + 4 * i);
        float4 hv;
        hv.x = bfb2f(hu.x); hv.y = bfb2f(hu.y); hv.z = bfb2f(hu.z); hv.w = bfb2f(hu.w);
        *(float4*)&xs[grp][4 * i] = hv;
        float a0 = wl[512 + 2 * i], a1 = wl[512 + 2 * i + 1];
#pragma unroll
        for (int k = 0; k < 32; k += 4) {
            const float4 xv = *(const float4*)&xs[grp][k];
            const float2 u0 = *(const float2*)&wl[(k + 0) * 16 + 2 * i];
            const float2 u1 = *(const float2*)&wl[(k + 1) * 16 + 2 * i];
            const float2 u2 = *(const float2*)&wl[(k + 2) * 16 + 2 * i];
            const float2 u3 = *(const float2*)&wl[(k + 3) * 16 + 2 * i];
            a0 += xv.x * u0.x + xv.y * u1.x + xv.z * u2.x + xv.w * u3.x;
            a1 += xv.x * u0.y + xv.y * u1.y + xv.z * u2.y + xv.w * u3.y;
        }
        a0 = fmaxf(a0, 0.f); a1 = fmaxf(a1, 0.f);
        *(float2*)&xs[grp][32 + 2 * i] = make_float2(a0, a1);
        float c0 = wl[784 + 2 * i], c1 = wl[784 + 2 * i + 1];
#pragma unroll
        for (int k = 0; k < 16; k += 4) {
            const float4 xv = *(const float4*)&xs[grp][32 + k];
            const float2 u0 = *(const float2*)&wl[528 + (k + 0) * 16 + 2 * i];
            const float2 u1 = *(const float2*)&wl[528 + (k + 1) * 16 + 2 * i];
            const float2 u2 = *(const float2*)&wl[528 + (k + 2) * 16 + 2 * i];
            const float2 u3 = *(const float2*)&wl[528 + (k + 3) * 16 + 2 * i];
            c0 += xv.x * u0.x + xv.y * u1.x + xv.z * u2.x + xv.w * u3.x;
            c1 += xv.x * u0.y + xv.y * u1.y + xv.z * u2.y + xv.w * u3.y;
        }
        c0 = fmaxf(c0, 0.f); c1 = fmaxf(c1, 0.f);
        float pv = c0 * wl[800 + 2 * i] + c1 * wl[800 + 2 * i + 1];
        pv += __shfl_xor(pv, 1, 8);
        pv += __shfl_xor(pv, 2, 8);
        pv += __shfl_xor(pv, 4, 8);
        const float occv = pv + wl[816];
        if (t < len) {
            const float inv = 1.f / capacity[l2p[p * 8 + t]];
            qd += occv * inv;
            ts += inv;
        }
    }
    if (i == 0) {
        const float res = qd + (traffic[p] / packets[p]) * ts;
        if (outf32) ((float*)out)[p] = res;
        else        ((bf16*)out)[p] = __float2bfloat16(res);
    }
}

// ---------------- launcher ---------------------------------------------------

extern "C" void kernel_launch(void* const* d_in, const int* in_sizes, int n_in,
                              void* d_out, int out_size, void* d_ws, size_t ws_size,
                              hipStream_t stream)
{
    static const int CVT_N[40] = {
        50000,50000,50000,50000,50000,50000,50000,50000,50000,50000,
        2000,6000,6000,
        544,32,1024,32, 160,32,1024,32, 160,32,1024,32,
        2048,1024,32, 1024,1024,32, 1024,1024,32,
        512,16,256,16,16,1};

    const int*  length   = (const int*)d_in[13];
    const int*  model    = (const int*)d_in[14];
    const int*  policy   = (const int*)d_in[15];
    const int*  priority = (const int*)d_in[16];
    const int*  q2p      = (const int*)d_in[17];
    const int*  l2p      = (const int*)d_in[18];
    const int*  p2l      = (const int*)d_in[19];
    const int*  p2l_deg  = (const int*)d_in[20];
    const int*  p2q      = (const int*)d_in[21];
    const int*  p2q_deg  = (const int*)d_in[22];
    const int*  q2l      = (const int*)d_in[23];

    // float-tensor table: d_in[0..12] data, d_in[24..50] weights
    CvtArgs ca;
    for (int i = 0; i < 13; i++) ca.p[i] = d_in[i];
    for (int i = 0; i < 27; i++) ca.p[13 + i] = d_in[24 + i];

    int off[41]; off[0] = 0;
    for (int i = 0; i < 40; i++) off[i + 1] = off[i] + CVT_N[i];
    int nblk = 0;
    for (int i = 0; i < 40; i++) nblk += (CVT_N[i] + 255) / 256;

    float* ws = (float*)d_ws;
    const float* c_traffic    = ws + off[0];
    const float* c_packets    = ws + off[1];
    const float* c_eq_lambda  = ws + off[2];
    const float* c_apl        = ws + off[3];
    const float* c_emf        = ws + off[4];
    const float* c_plo        = ws + off[5];
    const float* c_atoff      = ws + off[6];
    const float* c_aton       = ws + off[7];
    const float* c_ar_a       = ws + off[8];
    const float* c_sigma      = ws + off[9];
    const float* c_capacity   = ws + off[10];
    const float* c_queue_size = ws + off[11];
    const float* c_weight     = ws + off[12];
    const float* c_pe_w1 = ws + off[13]; const float* c_pe_b1 = ws + off[14];
    const float* c_pe_w2 = ws + off[15]; const float* c_pe_b2 = ws + off[16];
    const float* c_le_w1 = ws + off[17]; const float* c_le_b1 = ws + off[18];
    const float* c_le_w2 = ws + off[19]; const float* c_le_b2 = ws + off[20];
    const float* c_qe_w1 = ws + off[21]; const float* c_qe_b1 = ws + off[22];
    const float* c_qe_w2 = ws + off[23]; const float* c_qe_b2 = ws + off[24];
    const float* c_prW = ws + off[25]; const float* c_prU = ws + off[26];
    const float* c_prB = ws + off[27];
    const float* c_qrW = ws + off[28]; const float* c_qrU = ws + off[29];
    const float* c_qrB = ws + off[30];
    const float* c_lrW = ws + off[31]; const float* c_lrU = ws + off[32];
    const float* c_lrB = ws + off[33];
    const float* c_ro_w1 = ws + off[34]; const float* c_ro_b1 = ws + off[35];
    const float* c_ro_w2 = ws + off[36]; const float* c_ro_b2 = ws + off[37];
    const float* c_ro_w3 = ws + off[38]; const float* c_ro_b3 = ws + off[39];

    size_t base = ((size_t)off[40] + 63) & ~(size_t)63;     // 526272 floats
    float* path_state  = ws + base;                          // P*32
    float* queue_state = path_state + (size_t)P_ * 32;       // NQ*32
    float* link_state  = queue_state + (size_t)NQ_ * 32;     // NL*32
    float* zq          = link_state + (size_t)NL_ * 32;      // NQ*32
    float* zl          = zq + (size_t)NQ_ * 32;              // NL*32
    u16*   pss         = (u16*)(zl + (size_t)NL_ * 32);      // P*256 bf16
    // total ws: ~10.6 MB (f32 region) + 25.6 MB (pss) = ~36.2 MB

    k_convert<<<nblk, 256, 0, stream>>>(ca, ws);

    k_path_embed<<<(P_ + 255) / 256, 256, 0, stream>>>(
        c_traffic, c_packets, c_eq_lambda, c_apl, c_emf, c_plo, c_atoff, c_aton,
        c_ar_a, c_sigma, model, c_pe_w1, c_pe_b1, c_pe_w2, c_pe_b2, path_state);
    k_queue_embed<<<(NQ_ + 255) / 256, 256, 0, stream>>>(
        c_queue_size, c_weight, priority, c_qe_w1, c_qe_b1, c_qe_w2, c_qe_b2,
        queue_state);
    k_link_embed<<<NL_ / 4, 256, 0, stream>>>(
        c_traffic, c_capacity, policy, p2l, p2l_deg,
        c_le_w1, c_le_b1, c_le_w2, c_le_b2, link_state);
    k_zprep<<<(NQ_ + NL_ + 31) / 32, 256, 0, stream>>>(
        queue_state, link_state, c_prW, c_prB, zq, zl);

    for (int it = 0; it < ITERS_; ++it) {
        k_path_rnn<<<(P_ + 31) / 32, 256, 0, stream>>>(
            q2p, l2p, length, c_prU, zq, zl, path_state, pss);
        k_queue_update<<<NQ_ / 4, 256, 0, stream>>>(
            p2q, p2q_deg, c_qrW, c_qrU, c_qrB, c_prW, c_prB,
            pss, queue_state, zq);
        k_link_update<<<NL_ / 4, 256, 0, stream>>>(
            q2l, c_lrW, c_lrU, c_lrB, c_prW + 1024,
            queue_state, link_state, zl);
    }

    k_readout<<<(P_ + 31) / 32, 256, 0, stream>>>(
        d_in[0], c_traffic, c_packets, c_capacity, l2p, length,
        c_ro_w1, c_ro_b1, c_ro_w2, c_ro_b2, c_ro_w3, c_ro_b3, pss, d_out);
}